// Round 2
// baseline (245.390 us; speedup 1.0000x reference)
//
#include <hip/hip_runtime.h>

typedef _Float16 f16x8 __attribute__((ext_vector_type(8)));
typedef _Float16 f16x4 __attribute__((ext_vector_type(4)));
typedef short s16x4 __attribute__((ext_vector_type(4)));
typedef float f32x4 __attribute__((ext_vector_type(4)));

#define MFMA_K32(a, b, c) __builtin_amdgcn_mfma_f32_16x16x32_f16(a, b, c, 0, 0, 0)
#define MFMA_BF(a, b, c)  __builtin_amdgcn_mfma_f32_16x16x16bf16_1k(a, b, c, 0, 0, 0)
#define MFMA_F16(a, b, c) __builtin_amdgcn_mfma_f32_16x16x16f16(a, b, c, 0, 0, 0)

// B=8, N=3136, C=256, Ci=128, M=1568, NT=25088 rows. I/O fp32.
// Fragment-major internals (every hot load = base + lane*16B):
//   theta_f [1568 tiles][kc 4][lane 64][8]          (f16)
//   phi_f [8][chunk 49][kvt 2][kc 4][lane 64][8]    (f16)
//   g_f   [8][chunk 49][ct 8][lane 64][half 2][4]   (bf16) == V A-frag
//   wt_f  [3][ct 8][kc 8][lane 64][8]               (f16)
//   wfT_f [ctile 16][lane 64][kc2 8][4]             (f16) == w_final^T A-frag
// Softmax: static-shift (no online max): p = exp2(s*log2e - 104), P/V bf16.
// k_attn: SPLIT-KV. Block = 256 (4 waves), all 4 waves share the same 4
// m-tiles (64 Q rows); wave w scans chunks c ≡ w (mod 4) straight from L2
// (no LDS staging, phi reg-dbuf). Static shift => partial O / partial l are
// additive: 4-step LDS tree combine (66 KB, 4 barriers), then wave w
// normalizes + runs the fused w_final epilogue for m-tile w. 1568 waves,
// VGPR<=256 -> 2 waves/SIMD: latency hiding that round-1's 392 waves lacked.

__device__ __forceinline__ f16x8 ld8f(const float* __restrict__ p) {
    f32x4 a = *(const f32x4*)p;
    f32x4 b = *(const f32x4*)(p + 4);
    f16x8 r;
    r[0] = (_Float16)a[0]; r[1] = (_Float16)a[1];
    r[2] = (_Float16)a[2]; r[3] = (_Float16)a[3];
    r[4] = (_Float16)b[0]; r[5] = (_Float16)b[1];
    r[6] = (_Float16)b[2]; r[7] = (_Float16)b[3];
    return r;
}
__device__ __forceinline__ unsigned f2bf_rne(float f) {
    unsigned u = __float_as_uint(f);
    return (u + 0x7FFFu + ((u >> 16) & 1u)) >> 16;
}
__device__ __forceinline__ int bfpack_rtz(float lo, float hi) {
    return (int)((__float_as_uint(hi) & 0xFFFF0000u) | (__float_as_uint(lo) >> 16));
}

// ---------------------------------------------------------------------------
// Prep: weights fp32 -> f16, fragment-major.  grid 512, block 256.
// wfT: A-frag of w_final^T: value wf[Ci=kc2*16+q*4+jj][col=ct*16+t]
//      at [ct*2048 + lane*32 + kc2*4 + jj].
// ---------------------------------------------------------------------------
__global__ void k_prep(const float* __restrict__ wt, const float* __restrict__ wp,
                       const float* __restrict__ wg, const float* __restrict__ wf,
                       _Float16* __restrict__ wt_f, _Float16* __restrict__ wfT_f) {
    int i = blockIdx.x * 256 + threadIdx.x;  // 0..131071
    int w = i >> 15, idx = i & 32767;
    if (w < 3) {
        const float* src = (w == 0) ? wt : (w == 1) ? wp : wg;
        int k = idx >> 7, n = idx & 127;
        int ct = n >> 4, tt = n & 15, kc = k >> 5, qq = (k >> 3) & 3, jj = k & 7;
        wt_f[((w * 8 + ct) * 8 + kc) * 512 + (qq * 16 + tt) * 8 + jj] = (_Float16)src[idx];
    } else {
        int k = idx >> 8, n = idx & 255;        // k = Ci 0..127, n = out col 0..255
        int ct = n >> 4, tt = n & 15;
        int kc2 = k >> 4, qq = (k >> 2) & 3, jj = k & 3;
        wfT_f[ct * 2048 + (qq * 16 + tt) * 32 + kc2 * 4 + jj] = (_Float16)wf[idx];
    }
}

// ---------------------------------------------------------------------------
// Fused projections; maxpool(2) fused; fragment-major outputs.
// grid 784, block 128 (2 waves x 16 rows).  (unchanged)
// ---------------------------------------------------------------------------
__global__ __launch_bounds__(128) void k_proj(
    const float* __restrict__ x,        // [25088][256] fp32
    const _Float16* __restrict__ wt_f,  // [3][8][8][512]
    _Float16* __restrict__ theta_f,     // [1568][2048]
    _Float16* __restrict__ phi_f,       // [8][49][4096]
    short* __restrict__ g_f)            // [8][49][4096] bf16
{
    const int r0   = blockIdx.x * 32;
    const int wave = threadIdx.x >> 6;
    const int lane = threadIdx.x & 63;
    const int q = lane >> 4, t = lane & 15;

    const int mrow = r0 + wave * 16 + t;
    f16x8 af[8];
#pragma unroll
    for (int kc = 0; kc < 8; ++kc)
        af[kc] = ld8f(x + mrow * 256 + kc * 32 + q * 8);

    const f32x4 zero = {0.f, 0.f, 0.f, 0.f};
    f32x4 acc[3][8];
#pragma unroll
    for (int w = 0; w < 3; ++w)
#pragma unroll
        for (int ct = 0; ct < 8; ++ct) acc[w][ct] = zero;

#pragma unroll
    for (int w = 0; w < 3; ++w)
#pragma unroll
        for (int ct = 0; ct < 8; ++ct) {
            const _Float16* Wc = wt_f + ((w * 8 + ct) * 8) * 512 + lane * 8;
#pragma unroll
            for (int kc = 0; kc < 8; ++kc)
                acc[w][ct] = MFMA_K32(af[kc], *(const f16x8*)(Wc + kc * 512), acc[w][ct]);
        }

    // theta -> fragment-major tile
    _Float16* tb = theta_f + (blockIdx.x * 2 + wave) * 2048;
#pragma unroll
    for (int ct = 0; ct < 8; ++ct) {
        const int off = (ct >> 1) * 512 + ((ct & 1) * 2 + (t >> 3)) * 128 + (t & 7);
#pragma unroll
        for (int r = 0; r < 4; ++r)
            tb[off + (q * 4 + r) * 8] = (_Float16)acc[0][ct][r];
    }

    const int b     = blockIdx.x / 98;
    const int mIdx  = blockIdx.x % 98;
    const int chunk = mIdx >> 1;
    const int h     = mIdx & 1;          // bit4 of pooled row within chunk
    const int ttp   = wave * 8 + q * 2;  // kv' = pooled row & 15 (even)

    _Float16* pcb = phi_f + (b * 49 + chunk) * 4096;
#pragma unroll
    for (int ct = 0; ct < 8; ++ct) {
        const int kc = ct >> 1;
        const int qq = (ct & 1) * 2 + (t >> 3);
        const int j  = t & 7;
        const int off = (h * 4 + kc) * 512 + (qq * 16 + ttp) * 8 + j;
        pcb[off]     = (_Float16)fmaxf(acc[1][ct][0], acc[1][ct][1]);
        pcb[off + 8] = (_Float16)fmaxf(acc[1][ct][2], acc[1][ct][3]);
    }

    // g: V A/B-frag: lane = qv*16 + ci15, j8 = h*4 + (kv'&3)
    short* gcb = g_f + (b * 49 + chunk) * 4096;
    const int qv  = wave * 2 + (q >> 1);   // kv' >> 2
    const int jj0 = (q & 1) * 2;           // kv' & 3 (even)
#pragma unroll
    for (int ct = 0; ct < 8; ++ct) {
        unsigned lo = f2bf_rne(fmaxf(acc[2][ct][0], acc[2][ct][1]));
        unsigned hi = f2bf_rne(fmaxf(acc[2][ct][2], acc[2][ct][3]));
        *(unsigned*)(gcb + ct * 512 + (qv * 16 + t) * 8 + h * 4 + jj0) = lo | (hi << 16);
    }
}

// ---------------------------------------------------------------------------
// Attention + final, fused, split-KV.  grid 392 (8 b x 49), block 256.
// ---------------------------------------------------------------------------
#define LOADKV(DST, SRC) { _Pragma("unroll") \
    for (int j = 0; j < 8; ++j) DST[j] = *(const f16x8*)((SRC) + j * 512 + lane * 8); }

#define QKSM(PH) { \
    f32x4 st0[4], st1[4]; \
    _Pragma("unroll") for (int m = 0; m < 4; ++m) { st0[m] = zero; st1[m] = zero; } \
    __builtin_amdgcn_s_setprio(1); \
    _Pragma("unroll") for (int kc = 0; kc < 4; ++kc) \
      _Pragma("unroll") for (int m = 0; m < 4; ++m) { \
        st0[m] = MFMA_K32(PH[kc],     qf[m][kc], st0[m]); \
        st1[m] = MFMA_K32(PH[4 + kc], qf[m][kc], st1[m]); } \
    __builtin_amdgcn_s_setprio(0); \
    _Pragma("unroll") for (int m = 0; m < 4; ++m) { \
      f32x4 p0, p1; \
      _Pragma("unroll") for (int r = 0; r < 4; ++r) { \
        p0[r] = exp2f(st0[m][r] * L2E - SHIFT); \
        p1[r] = exp2f(st1[m][r] * L2E - SHIFT); } \
      lsum[m] += ((p0[0] + p0[1]) + (p0[2] + p0[3])) \
               + ((p1[0] + p1[1]) + (p1[2] + p1[3])); \
      u[m][0].i2[0] = bfpack_rtz(p0[0], p0[1]); \
      u[m][0].i2[1] = bfpack_rtz(p0[2], p0[3]); \
      u[m][1].i2[0] = bfpack_rtz(p1[0], p1[1]); \
      u[m][1].i2[1] = bfpack_rtz(p1[2], p1[3]); } }

// swapped operands: A = V (g frag), B = P  -> o'[Ci][qrow] (transposed)
#define PV(AG) { \
    __builtin_amdgcn_s_setprio(1); \
    _Pragma("unroll") for (int ct = 0; ct < 8; ++ct) { \
      union { f16x8 f; s16x4 s[2]; } uv; uv.f = AG[ct]; \
      _Pragma("unroll") for (int m = 0; m < 4; ++m) { \
        o[m][ct] = MFMA_BF(uv.s[0], u[m][0].v, o[m][ct]); \
        o[m][ct] = MFMA_BF(uv.s[1], u[m][1].v, o[m][ct]); } } \
    __builtin_amdgcn_s_setprio(0); }

__global__ __launch_bounds__(256, 2) void k_attn(
    const _Float16* __restrict__ theta_f,  // [1568][2048]
    const _Float16* __restrict__ phi_f,    // [8][49][4096]
    const short* __restrict__ g_f,         // [8][49][4096] bf16
    const _Float16* __restrict__ wfT_f,    // [16][64][8][4]
    const float* __restrict__ x,           // [25088][256]
    float* __restrict__ out)               // [25088][256]
{
    const int blk  = blockIdx.x;          // 392 = 8 batches x 49
    const int b    = blk & 7;             // XCD affinity
    const int blkm = blk >> 3;            // 0..48
    const int wave = threadIdx.x >> 6;
    const int lane = threadIdx.x & 63;
    const int q = lane >> 4, t = lane & 15;

    __shared__ __align__(16) float cbuf[2][8192];  // 64 KB
    __shared__ float lbuf[2][256];                 //  2 KB

    const int tIdx0 = b * 196 + blkm * 4;           // 4 consecutive m-tiles
    const _Float16* ph = phi_f + b * 200704;
    const _Float16* gt = (const _Float16*)(g_f + b * 200704);

    // Q fragments: 4 tiles x 4 kc, register-resident for the whole scan
    f16x8 qf[4][4];
#pragma unroll
    for (int m = 0; m < 4; ++m)
#pragma unroll
        for (int kc = 0; kc < 4; ++kc)
            qf[m][kc] = *(const f16x8*)(theta_f + (tIdx0 + m) * 2048 + kc * 512 + lane * 8);

    const f32x4 zero = {0.f, 0.f, 0.f, 0.f};
    f32x4 o[4][8];
#pragma unroll
    for (int m = 0; m < 4; ++m)
#pragma unroll
        for (int ct = 0; ct < 8; ++ct) o[m][ct] = zero;
    float lsum[4] = {0.f, 0.f, 0.f, 0.f};
    union ubf { int i2[2]; s16x4 v; } u[4][2];
    const float L2E = 1.44269504f, SHIFT = 104.0f;

    // wave w scans chunks c ≡ w (mod 4): 12 chunks each + chunk 48 on wave 0
    f16x8 phA[8], phB[8], ag[8];
    int c = wave;
    LOADKV(phA, ph + c * 4096);

#pragma unroll 1
    for (int k = 0; k < 6; ++k) {            // covers c, c+4 for c = wave+8k
        LOADKV(ag, gt + c * 4096);
        QKSM(phA);                           // chunk c
        LOADKV(phB, ph + (c + 4) * 4096);    // prefetch under PV
        PV(ag);
        LOADKV(ag, gt + (c + 4) * 4096);
        QKSM(phB);                           // chunk c+4
        if (c + 8 <= 48) LOADKV(phA, ph + (c + 8) * 4096);  // uniform branch
        PV(ag);
        c += 8;
    }
    if (wave == 0) {                         // tail: chunk 48 (phA holds it)
        LOADKV(ag, gt + 48 * 4096);
        QKSM(phA);
        PV(ag);
    }

    // ---- cross-wave combine: static shift => partials simply add ----
    if (wave >= 2) {
        float* cb = cbuf[wave - 2];
#pragma unroll
        for (int m = 0; m < 4; ++m) {
#pragma unroll
            for (int ct = 0; ct < 8; ++ct)
                *(f32x4*)&cb[(m * 8 + ct) * 256 + lane * 4] = o[m][ct];
            lbuf[wave - 2][m * 64 + lane] = lsum[m];
        }
    }
    __syncthreads();
    if (wave < 2) {                          // 0 += wave2, 1 += wave3
        const float* cb = cbuf[wave];
#pragma unroll
        for (int m = 0; m < 4; ++m) {
#pragma unroll
            for (int ct = 0; ct < 8; ++ct)
                o[m][ct] += *(const f32x4*)&cb[(m * 8 + ct) * 256 + lane * 4];
            lsum[m] += lbuf[wave][m * 64 + lane];
        }
    }
    __syncthreads();
    if (wave == 1) {
        float* cb = cbuf[0];
#pragma unroll
        for (int m = 0; m < 4; ++m) {
#pragma unroll
            for (int ct = 0; ct < 8; ++ct)
                *(f32x4*)&cb[(m * 8 + ct) * 256 + lane * 4] = o[m][ct];
            lbuf[0][m * 64 + lane] = lsum[m];
        }
    }
    __syncthreads();
    f32x4 ow[8];
    float lw;
    if (wave == 0) {
        const float* cb = cbuf[0];
#pragma unroll
        for (int m = 0; m < 4; ++m) {
#pragma unroll
            for (int ct = 0; ct < 8; ++ct)
                o[m][ct] += *(const f32x4*)&cb[(m * 8 + ct) * 256 + lane * 4];
            lsum[m] += lbuf[0][m * 64 + lane];
        }
        // publish combined m=1..3 for the other waves' epilogues
        float* cw = cbuf[1];
#pragma unroll
        for (int m = 1; m < 4; ++m) {
#pragma unroll
            for (int ct = 0; ct < 8; ++ct)
                *(f32x4*)&cw[((m - 1) * 8 + ct) * 256 + lane * 4] = o[m][ct];
            lbuf[1][(m - 1) * 64 + lane] = lsum[m];
        }
#pragma unroll
        for (int ct = 0; ct < 8; ++ct) ow[ct] = o[0][ct];
        lw = lsum[0];
    }
    __syncthreads();
    if (wave > 0) {
        const float* cw = cbuf[1];
#pragma unroll
        for (int ct = 0; ct < 8; ++ct)
            ow[ct] = *(const f32x4*)&cw[((wave - 1) * 8 + ct) * 256 + lane * 4];
        lw = lbuf[1][(wave - 1) * 64 + lane];
    }

    // softmax denom for this wave's m-tile; inv is a per-lane scalar
    float lf = lw;
    lf += __shfl_xor(lf, 16);
    lf += __shfl_xor(lf, 32);
    const float inv = 1.0f / lf;

    // ow[ct][r] = y[row t][Ci = ct*16+4q+r] -> exactly the K16 B-frag
    f16x4 yf[8];
#pragma unroll
    for (int ct = 0; ct < 8; ++ct)
#pragma unroll
        for (int r = 0; r < 4; ++r)
            yf[ct][r] = (_Float16)(ow[ct][r] * inv);

    // fused final for m-tile `wave`: out = x + y @ w_final
    const int row = tIdx0 * 16 + wave * 16 + t;
#pragma unroll 1
    for (int ctile = 0; ctile < 16; ++ctile) {
        union { f16x8 v8; f16x4 v4[2]; } w[4];
#pragma unroll
        for (int p = 0; p < 4; ++p)
            w[p].v8 = *(const f16x8*)(wfT_f + ctile * 2048 + lane * 32 + p * 8);
        f32x4 acc = zero;
#pragma unroll
        for (int kc2 = 0; kc2 < 8; ++kc2)
            acc = MFMA_F16(w[kc2 >> 1].v4[kc2 & 1], yf[kc2], acc);
        const int col = ctile * 16 + q * 4;
        f32x4 xv = *(const f32x4*)(x + row * 256 + col);
        *(f32x4*)(out + row * 256 + col) = acc + xv;
    }
}

// ---------------------------------------------------------------------------
extern "C" void kernel_launch(void* const* d_in, const int* in_sizes, int n_in,
                              void* d_out, int out_size, void* d_ws, size_t ws_size,
                              hipStream_t stream) {
    const float* x  = (const float*)d_in[0];
    const float* wt = (const float*)d_in[1];
    const float* wp = (const float*)d_in[2];
    const float* wg = (const float*)d_in[3];
    const float* wf = (const float*)d_in[4];
    float* out = (float*)d_out;

    _Float16* ws      = (_Float16*)d_ws;
    _Float16* wt_f    = ws;               //  98304
    _Float16* wfT_f   = ws + 98304;       //  32768
    _Float16* theta_f = ws + 131072;      //  3211264
    _Float16* phi_f   = ws + 3342336;     //  1605632
    short*    g_f     = (short*)(ws + 4947968);  // 1605632
    // total 6553600 halves = ~13.1 MB

    k_prep<<<dim3(512), 256, 0, stream>>>(wt, wp, wg, wf, wt_f, wfT_f);
    k_proj<<<dim3(784), 128, 0, stream>>>(x, wt_f, theta_f, phi_f, g_f);
    k_attn<<<dim3(392), 256, 0, stream>>>(theta_f, phi_f, g_f, wfT_f, x, out);
}

// Round 3
// 166.379 us; speedup vs baseline: 1.4749x; 1.4749x over previous
//
#include <hip/hip_runtime.h>

typedef _Float16 f16x8 __attribute__((ext_vector_type(8)));
typedef _Float16 f16x4 __attribute__((ext_vector_type(4)));
typedef short s16x4 __attribute__((ext_vector_type(4)));
typedef float f32x4 __attribute__((ext_vector_type(4)));

#define MFMA_K32(a, b, c) __builtin_amdgcn_mfma_f32_16x16x32_f16(a, b, c, 0, 0, 0)
#define MFMA_BF(a, b, c)  __builtin_amdgcn_mfma_f32_16x16x16bf16_1k(a, b, c, 0, 0, 0)
#define MFMA_F16(a, b, c) __builtin_amdgcn_mfma_f32_16x16x16f16(a, b, c, 0, 0, 0)

// B=8, N=3136, C=256, Ci=128, M=1568, NT=25088 rows. I/O fp32.
// Fragment-major internals (every hot load = base + lane*16B):
//   theta_f [1568 tiles][kc 4][lane 64][8]          (f16)
//   phi_f [8][chunk 49][kvt 2][kc 4][lane 64][8]    (f16)
//   g_f   [8][chunk 49][ct 8][lane 64][half 2][4]   (bf16) == V A-frag
//   wt_f  [3][ct 8][kc 8][lane 64][8]               (f16)
//   wfT_f [ctile 16][lane 64][kc2 8][4]             (f16) == w_final^T A-frag
// Softmax: static-shift (no online max): p = exp2(s*log2e - 104), P/V bf16.
// k_attn: SPLIT-KV. Block = 256 (4 waves), all 4 waves share the same 4
// m-tiles (64 Q rows); wave w scans chunks c ≡ w (mod 4) straight from L2
// (no LDS staging, phi reg-dbuf). Static shift => partial O / partial l are
// additive: LDS tree combine, then wave w normalizes + runs the fused
// w_final epilogue for m-tile w.
// ROUND-3 FIX: no min-occupancy launch_bounds. Round 2's (256,2) capped
// VGPR at 128 vs ~280 demand -> ~400 MB scratch spill traffic (FETCH 218MB,
// WRITE 189MB). Round 1's identical body fit 208 VGPR spill-free; letting
// the allocator float lands ~220 -> 2 waves/SIMD without spills.

__device__ __forceinline__ f16x8 ld8f(const float* __restrict__ p) {
    f32x4 a = *(const f32x4*)p;
    f32x4 b = *(const f32x4*)(p + 4);
    f16x8 r;
    r[0] = (_Float16)a[0]; r[1] = (_Float16)a[1];
    r[2] = (_Float16)a[2]; r[3] = (_Float16)a[3];
    r[4] = (_Float16)b[0]; r[5] = (_Float16)b[1];
    r[6] = (_Float16)b[2]; r[7] = (_Float16)b[3];
    return r;
}
__device__ __forceinline__ unsigned f2bf_rne(float f) {
    unsigned u = __float_as_uint(f);
    return (u + 0x7FFFu + ((u >> 16) & 1u)) >> 16;
}
__device__ __forceinline__ int bfpack_rtz(float lo, float hi) {
    return (int)((__float_as_uint(hi) & 0xFFFF0000u) | (__float_as_uint(lo) >> 16));
}

// ---------------------------------------------------------------------------
// Prep: weights fp32 -> f16, fragment-major.  grid 512, block 256.
// wfT: A-frag of w_final^T: value wf[Ci=kc2*16+q*4+jj][col=ct*16+t]
//      at [ct*2048 + lane*32 + kc2*4 + jj].
// ---------------------------------------------------------------------------
__global__ void k_prep(const float* __restrict__ wt, const float* __restrict__ wp,
                       const float* __restrict__ wg, const float* __restrict__ wf,
                       _Float16* __restrict__ wt_f, _Float16* __restrict__ wfT_f) {
    int i = blockIdx.x * 256 + threadIdx.x;  // 0..131071
    int w = i >> 15, idx = i & 32767;
    if (w < 3) {
        const float* src = (w == 0) ? wt : (w == 1) ? wp : wg;
        int k = idx >> 7, n = idx & 127;
        int ct = n >> 4, tt = n & 15, kc = k >> 5, qq = (k >> 3) & 3, jj = k & 7;
        wt_f[((w * 8 + ct) * 8 + kc) * 512 + (qq * 16 + tt) * 8 + jj] = (_Float16)src[idx];
    } else {
        int k = idx >> 8, n = idx & 255;        // k = Ci 0..127, n = out col 0..255
        int ct = n >> 4, tt = n & 15;
        int kc2 = k >> 4, qq = (k >> 2) & 3, jj = k & 3;
        wfT_f[ct * 2048 + (qq * 16 + tt) * 32 + kc2 * 4 + jj] = (_Float16)wf[idx];
    }
}

// ---------------------------------------------------------------------------
// Fused projections; maxpool(2) fused; fragment-major outputs.
// grid 784, block 128 (2 waves x 16 rows).  (unchanged)
// ---------------------------------------------------------------------------
__global__ __launch_bounds__(128) void k_proj(
    const float* __restrict__ x,        // [25088][256] fp32
    const _Float16* __restrict__ wt_f,  // [3][8][8][512]
    _Float16* __restrict__ theta_f,     // [1568][2048]
    _Float16* __restrict__ phi_f,       // [8][49][4096]
    short* __restrict__ g_f)            // [8][49][4096] bf16
{
    const int r0   = blockIdx.x * 32;
    const int wave = threadIdx.x >> 6;
    const int lane = threadIdx.x & 63;
    const int q = lane >> 4, t = lane & 15;

    const int mrow = r0 + wave * 16 + t;
    f16x8 af[8];
#pragma unroll
    for (int kc = 0; kc < 8; ++kc)
        af[kc] = ld8f(x + mrow * 256 + kc * 32 + q * 8);

    const f32x4 zero = {0.f, 0.f, 0.f, 0.f};
    f32x4 acc[3][8];
#pragma unroll
    for (int w = 0; w < 3; ++w)
#pragma unroll
        for (int ct = 0; ct < 8; ++ct) acc[w][ct] = zero;

#pragma unroll
    for (int w = 0; w < 3; ++w)
#pragma unroll
        for (int ct = 0; ct < 8; ++ct) {
            const _Float16* Wc = wt_f + ((w * 8 + ct) * 8) * 512 + lane * 8;
#pragma unroll
            for (int kc = 0; kc < 8; ++kc)
                acc[w][ct] = MFMA_K32(af[kc], *(const f16x8*)(Wc + kc * 512), acc[w][ct]);
        }

    // theta -> fragment-major tile
    _Float16* tb = theta_f + (blockIdx.x * 2 + wave) * 2048;
#pragma unroll
    for (int ct = 0; ct < 8; ++ct) {
        const int off = (ct >> 1) * 512 + ((ct & 1) * 2 + (t >> 3)) * 128 + (t & 7);
#pragma unroll
        for (int r = 0; r < 4; ++r)
            tb[off + (q * 4 + r) * 8] = (_Float16)acc[0][ct][r];
    }

    const int b     = blockIdx.x / 98;
    const int mIdx  = blockIdx.x % 98;
    const int chunk = mIdx >> 1;
    const int h     = mIdx & 1;          // bit4 of pooled row within chunk
    const int ttp   = wave * 8 + q * 2;  // kv' = pooled row & 15 (even)

    _Float16* pcb = phi_f + (b * 49 + chunk) * 4096;
#pragma unroll
    for (int ct = 0; ct < 8; ++ct) {
        const int kc = ct >> 1;
        const int qq = (ct & 1) * 2 + (t >> 3);
        const int j  = t & 7;
        const int off = (h * 4 + kc) * 512 + (qq * 16 + ttp) * 8 + j;
        pcb[off]     = (_Float16)fmaxf(acc[1][ct][0], acc[1][ct][1]);
        pcb[off + 8] = (_Float16)fmaxf(acc[1][ct][2], acc[1][ct][3]);
    }

    // g: V A/B-frag: lane = qv*16 + ci15, j8 = h*4 + (kv'&3)
    short* gcb = g_f + (b * 49 + chunk) * 4096;
    const int qv  = wave * 2 + (q >> 1);   // kv' >> 2
    const int jj0 = (q & 1) * 2;           // kv' & 3 (even)
#pragma unroll
    for (int ct = 0; ct < 8; ++ct) {
        unsigned lo = f2bf_rne(fmaxf(acc[2][ct][0], acc[2][ct][1]));
        unsigned hi = f2bf_rne(fmaxf(acc[2][ct][2], acc[2][ct][3]));
        *(unsigned*)(gcb + ct * 512 + (qv * 16 + t) * 8 + h * 4 + jj0) = lo | (hi << 16);
    }
}

// ---------------------------------------------------------------------------
// Attention + final, fused, split-KV.  grid 392 (8 b x 49), block 256.
// ---------------------------------------------------------------------------
#define LOADKV(DST, SRC) { _Pragma("unroll") \
    for (int j = 0; j < 8; ++j) DST[j] = *(const f16x8*)((SRC) + j * 512 + lane * 8); }

#define QKSM(PH) { \
    f32x4 st0[4], st1[4]; \
    _Pragma("unroll") for (int m = 0; m < 4; ++m) { st0[m] = zero; st1[m] = zero; } \
    __builtin_amdgcn_s_setprio(1); \
    _Pragma("unroll") for (int kc = 0; kc < 4; ++kc) \
      _Pragma("unroll") for (int m = 0; m < 4; ++m) { \
        st0[m] = MFMA_K32(PH[kc],     qf[m][kc], st0[m]); \
        st1[m] = MFMA_K32(PH[4 + kc], qf[m][kc], st1[m]); } \
    __builtin_amdgcn_s_setprio(0); \
    _Pragma("unroll") for (int m = 0; m < 4; ++m) { \
      f32x4 p0, p1; \
      _Pragma("unroll") for (int r = 0; r < 4; ++r) { \
        p0[r] = exp2f(st0[m][r] * L2E - SHIFT); \
        p1[r] = exp2f(st1[m][r] * L2E - SHIFT); } \
      lsum[m] += ((p0[0] + p0[1]) + (p0[2] + p0[3])) \
               + ((p1[0] + p1[1]) + (p1[2] + p1[3])); \
      u[m][0].i2[0] = bfpack_rtz(p0[0], p0[1]); \
      u[m][0].i2[1] = bfpack_rtz(p0[2], p0[3]); \
      u[m][1].i2[0] = bfpack_rtz(p1[0], p1[1]); \
      u[m][1].i2[1] = bfpack_rtz(p1[2], p1[3]); } }

// swapped operands: A = V (g frag), B = P  -> o'[Ci][qrow] (transposed)
#define PV(AG) { \
    __builtin_amdgcn_s_setprio(1); \
    _Pragma("unroll") for (int ct = 0; ct < 8; ++ct) { \
      union { f16x8 f; s16x4 s[2]; } uv; uv.f = AG[ct]; \
      _Pragma("unroll") for (int m = 0; m < 4; ++m) { \
        o[m][ct] = MFMA_BF(uv.s[0], u[m][0].v, o[m][ct]); \
        o[m][ct] = MFMA_BF(uv.s[1], u[m][1].v, o[m][ct]); } } \
    __builtin_amdgcn_s_setprio(0); }

__global__ __launch_bounds__(256) void k_attn(
    const _Float16* __restrict__ theta_f,  // [1568][2048]
    const _Float16* __restrict__ phi_f,    // [8][49][4096]
    const short* __restrict__ g_f,         // [8][49][4096] bf16
    const _Float16* __restrict__ wfT_f,    // [16][64][8][4]
    const float* __restrict__ x,           // [25088][256]
    float* __restrict__ out)               // [25088][256]
{
    const int blk  = blockIdx.x;          // 392 = 8 batches x 49
    const int b    = blk & 7;             // XCD affinity
    const int blkm = blk >> 3;            // 0..48
    const int wave = threadIdx.x >> 6;
    const int lane = threadIdx.x & 63;
    const int q = lane >> 4, t = lane & 15;

    __shared__ __align__(16) float cbuf[2][8192];  // 64 KB
    __shared__ float lbuf[2][256];                 //  2 KB

    const int tIdx0 = b * 196 + blkm * 4;           // 4 consecutive m-tiles
    const _Float16* ph = phi_f + b * 200704;
    const _Float16* gt = (const _Float16*)(g_f + b * 200704);

    // Q fragments: 4 tiles x 4 kc, register-resident for the whole scan
    f16x8 qf[4][4];
#pragma unroll
    for (int m = 0; m < 4; ++m)
#pragma unroll
        for (int kc = 0; kc < 4; ++kc)
            qf[m][kc] = *(const f16x8*)(theta_f + (tIdx0 + m) * 2048 + kc * 512 + lane * 8);

    const f32x4 zero = {0.f, 0.f, 0.f, 0.f};
    f32x4 o[4][8];
#pragma unroll
    for (int m = 0; m < 4; ++m)
#pragma unroll
        for (int ct = 0; ct < 8; ++ct) o[m][ct] = zero;
    float lsum[4] = {0.f, 0.f, 0.f, 0.f};
    union ubf { int i2[2]; s16x4 v; } u[4][2];
    const float L2E = 1.44269504f, SHIFT = 104.0f;

    // wave w scans chunks c ≡ w (mod 4): 12 chunks each + chunk 48 on wave 0
    f16x8 phA[8], phB[8], ag[8];
    int c = wave;
    LOADKV(phA, ph + c * 4096);

#pragma unroll 1
    for (int k = 0; k < 6; ++k) {            // covers c, c+4 for c = wave+8k
        LOADKV(ag, gt + c * 4096);
        QKSM(phA);                           // chunk c
        LOADKV(phB, ph + (c + 4) * 4096);    // prefetch under PV
        PV(ag);
        LOADKV(ag, gt + (c + 4) * 4096);
        QKSM(phB);                           // chunk c+4
        if (c + 8 <= 48) LOADKV(phA, ph + (c + 8) * 4096);  // uniform branch
        PV(ag);
        c += 8;
    }
    if (wave == 0) {                         // tail: chunk 48 (phA holds it)
        LOADKV(ag, gt + 48 * 4096);
        QKSM(phA);
        PV(ag);
    }

    // ---- cross-wave combine: static shift => partials simply add ----
    if (wave >= 2) {
        float* cb = cbuf[wave - 2];
#pragma unroll
        for (int m = 0; m < 4; ++m) {
#pragma unroll
            for (int ct = 0; ct < 8; ++ct)
                *(f32x4*)&cb[(m * 8 + ct) * 256 + lane * 4] = o[m][ct];
            lbuf[wave - 2][m * 64 + lane] = lsum[m];
        }
    }
    __syncthreads();
    if (wave < 2) {                          // 0 += wave2, 1 += wave3
        const float* cb = cbuf[wave];
#pragma unroll
        for (int m = 0; m < 4; ++m) {
#pragma unroll
            for (int ct = 0; ct < 8; ++ct)
                o[m][ct] += *(const f32x4*)&cb[(m * 8 + ct) * 256 + lane * 4];
            lsum[m] += lbuf[wave][m * 64 + lane];
        }
    }
    __syncthreads();
    if (wave == 1) {
        float* cb = cbuf[0];
#pragma unroll
        for (int m = 0; m < 4; ++m) {
#pragma unroll
            for (int ct = 0; ct < 8; ++ct)
                *(f32x4*)&cb[(m * 8 + ct) * 256 + lane * 4] = o[m][ct];
            lbuf[0][m * 64 + lane] = lsum[m];
        }
    }
    __syncthreads();
    f32x4 ow[8];
    float lw;
    if (wave == 0) {
        const float* cb = cbuf[0];
#pragma unroll
        for (int m = 0; m < 4; ++m) {
#pragma unroll
            for (int ct = 0; ct < 8; ++ct)
                o[m][ct] += *(const f32x4*)&cb[(m * 8 + ct) * 256 + lane * 4];
            lsum[m] += lbuf[0][m * 64 + lane];
        }
        // publish combined m=1..3 for the other waves' epilogues
        float* cw = cbuf[1];
#pragma unroll
        for (int m = 1; m < 4; ++m) {
#pragma unroll
            for (int ct = 0; ct < 8; ++ct)
                *(f32x4*)&cw[((m - 1) * 8 + ct) * 256 + lane * 4] = o[m][ct];
            lbuf[1][(m - 1) * 64 + lane] = lsum[m];
        }
#pragma unroll
        for (int ct = 0; ct < 8; ++ct) ow[ct] = o[0][ct];
        lw = lsum[0];
    }
    __syncthreads();
    if (wave > 0) {
        const float* cw = cbuf[1];
#pragma unroll
        for (int ct = 0; ct < 8; ++ct)
            ow[ct] = *(const f32x4*)&cw[((wave - 1) * 8 + ct) * 256 + lane * 4];
        lw = lbuf[1][(wave - 1) * 64 + lane];
    }

    // softmax denom for this wave's m-tile; inv is a per-lane scalar
    float lf = lw;
    lf += __shfl_xor(lf, 16);
    lf += __shfl_xor(lf, 32);
    const float inv = 1.0f / lf;

    // ow[ct][r] = y[row t][Ci = ct*16+4q+r] -> exactly the K16 B-frag
    f16x4 yf[8];
#pragma unroll
    for (int ct = 0; ct < 8; ++ct)
#pragma unroll
        for (int r = 0; r < 4; ++r)
            yf[ct][r] = (_Float16)(ow[ct][r] * inv);

    // fused final for m-tile `wave`: out = x + y @ w_final
    const int row = tIdx0 * 16 + wave * 16 + t;
#pragma unroll 1
    for (int ctile = 0; ctile < 16; ++ctile) {
        union { f16x8 v8; f16x4 v4[2]; } w[4];
#pragma unroll
        for (int p = 0; p < 4; ++p)
            w[p].v8 = *(const f16x8*)(wfT_f + ctile * 2048 + lane * 32 + p * 8);
        f32x4 acc = zero;
#pragma unroll
        for (int kc2 = 0; kc2 < 8; ++kc2)
            acc = MFMA_F16(w[kc2 >> 1].v4[kc2 & 1], yf[kc2], acc);
        const int col = ctile * 16 + q * 4;
        f32x4 xv = *(const f32x4*)(x + row * 256 + col);
        *(f32x4*)(out + row * 256 + col) = acc + xv;
    }
}

// ---------------------------------------------------------------------------
extern "C" void kernel_launch(void* const* d_in, const int* in_sizes, int n_in,
                              void* d_out, int out_size, void* d_ws, size_t ws_size,
                              hipStream_t stream) {
    const float* x  = (const float*)d_in[0];
    const float* wt = (const float*)d_in[1];
    const float* wp = (const float*)d_in[2];
    const float* wg = (const float*)d_in[3];
    const float* wf = (const float*)d_in[4];
    float* out = (float*)d_out;

    _Float16* ws      = (_Float16*)d_ws;
    _Float16* wt_f    = ws;               //  98304
    _Float16* wfT_f   = ws + 98304;       //  32768
    _Float16* theta_f = ws + 131072;      //  3211264
    _Float16* phi_f   = ws + 3342336;     //  1605632
    short*    g_f     = (short*)(ws + 4947968);  // 1605632
    // total 6553600 halves = ~13.1 MB

    k_prep<<<dim3(512), 256, 0, stream>>>(wt, wp, wg, wf, wt_f, wfT_f);
    k_proj<<<dim3(784), 128, 0, stream>>>(x, wt_f, theta_f, phi_f, g_f);
    k_attn<<<dim3(392), 256, 0, stream>>>(theta_f, phi_f, g_f, wfT_f, x, out);
}